// Round 6
// baseline (779.265 us; speedup 1.0000x reference)
//
#include <hip/hip_runtime.h>

#define NN 100000
#define NE 3200000
#define ET (NE + NN)
#define NEG_SLOPE 0.2f

__device__ __forceinline__ float lrelu(float v) { return v > 0.f ? v : NEG_SLOPE * v; }

// bf16 <-> f32
__device__ __forceinline__ unsigned short f2bf(float x) {
    unsigned u = __float_as_uint(x);
    return (unsigned short)((u + 0x7fffu + ((u >> 16) & 1u)) >> 16);
}
__device__ __forceinline__ float bflo(unsigned u) { return __uint_as_float(u << 16); }
__device__ __forceinline__ float bfhi(unsigned u) { return __uint_as_float(u & 0xffff0000u); }

// ---------------- direct global-atomic CSR build ----------------
// deg (init 1 for self loop) -> hierarchical exclusive scan -> rowptr;
// self loop pre-placed at ssrc[rowptr[n]]; fill scatters real edges with
// p = atomicAdd(cur[d]). Within-node order is atomic-timing-dependent (the
// previous sort_kernel placement was too); summation tolerance absorbs it.

__global__ __launch_bounds__(256) void initdeg_kernel(int* __restrict__ deg) {
    int n = blockIdx.x * 256 + threadIdx.x;
    if (n < NN) deg[n] = 1;               // self loop
}

__global__ __launch_bounds__(256) void deg_kernel(const int* __restrict__ dst,
                                                  int* __restrict__ deg) {
    int stride = gridDim.x * 256;
    for (int k = blockIdx.x * 256 + threadIdx.x; k < NE; k += stride)
        atomicAdd(&deg[dst[k]], 1);
}

// scan phase 1: per-block (1024 nodes) exclusive scan, block totals out
__global__ __launch_bounds__(1024) void scan1_kernel(const int* __restrict__ deg,
                                                     int* __restrict__ rowptr,
                                                     int* __restrict__ tot) {
    __shared__ int t[1024];
    int n = blockIdx.x * 1024 + threadIdx.x;
    int s = (n < NN) ? deg[n] : 0;
    t[threadIdx.x] = s;
    __syncthreads();
    for (int off = 1; off < 1024; off <<= 1) {
        int v = (threadIdx.x >= off) ? t[threadIdx.x - off] : 0;
        __syncthreads();
        t[threadIdx.x] += v;
        __syncthreads();
    }
    if (n <= NN && n < (blockIdx.x + 1) * 1024)  // write local exclusive scan
        if (n < NN) rowptr[n] = t[threadIdx.x] - s;
    if (threadIdx.x == 1023) tot[blockIdx.x] = t[1023];
}

// scan phase 2: exclusive scan of block totals (<=128 blocks)
__global__ __launch_bounds__(128) void scan2_kernel(int* __restrict__ tot, int nb) {
    __shared__ int t[128];
    int i = threadIdx.x;
    int s = (i < nb) ? tot[i] : 0;
    t[i] = s;
    __syncthreads();
    for (int off = 1; off < 128; off <<= 1) {
        int v = (i >= off) ? t[i - off] : 0;
        __syncthreads();
        t[i] += v;
        __syncthreads();
    }
    if (i < nb) tot[i] = t[i] - s;
}

// scan phase 3: add block offset, place self loop, init cur
__global__ __launch_bounds__(1024) void scan3_kernel(int* __restrict__ rowptr,
                                                     const int* __restrict__ tot,
                                                     int* __restrict__ cur,
                                                     int* __restrict__ ssrc) {
    int n = blockIdx.x * 1024 + threadIdx.x;
    if (n >= NN) return;
    int r = rowptr[n] + tot[blockIdx.x];
    rowptr[n] = r;
    ssrc[r] = n;          // self loop first
    cur[n] = r + 1;
    if (n == 0) rowptr[NN] = ET;
}

__global__ __launch_bounds__(256) void fill_kernel(const int* __restrict__ src,
                                                   const int* __restrict__ dst,
                                                   int* __restrict__ cur,
                                                   int* __restrict__ ssrc) {
    int stride = gridDim.x * 256;
    for (int k = blockIdx.x * 256 + threadIdx.x; k < NE; k += stride) {
        int s = src[k], d = dst[k];
        int p = atomicAdd(&cur[d], 1);
        ssrc[p] = s;
    }
}

// ---------------- dense per-layer kernels ----------------

// fused GEMM + attention logits. Each thread computes 4 consecutive output
// features for one node: float4 x loads, float4 (b128) LDS W reads.
template <int FIN, int FOUT, int C>
__global__ __launch_bounds__(256) void gemm_attn_kernel(
    const float* __restrict__ x, const float* __restrict__ W,
    const float* __restrict__ a_src, const float* __restrict__ a_dst,
    unsigned short* __restrict__ h, float* __restrict__ esrc,
    float* __restrict__ edst, int N) {
    constexpr int HH = FOUT / C;
    constexpr int F4 = FOUT / 4;
    constexpr int TPH = C / 4;           // threads per head
    __shared__ __align__(16) float Ws[FIN * FOUT];
    for (int i = threadIdx.x; i < FIN * FOUT; i += blockDim.x) Ws[i] = W[i];
    __syncthreads();
    int idx = blockIdx.x * blockDim.x + threadIdx.x;
    if (idx >= N * F4) return;
    int n = idx / F4, f4 = idx - n * F4;
    int fb = 4 * f4;
    const float4* xr = (const float4*)(x + (long)n * FIN);
    float a0 = 0.f, a1 = 0.f, a2 = 0.f, a3 = 0.f;
#pragma unroll
    for (int k4 = 0; k4 < FIN / 4; ++k4) {
        float4 xv = xr[k4];
        const float* wr = &Ws[(4 * k4) * FOUT + fb];
        float4 w0 = *(const float4*)(wr);
        float4 w1 = *(const float4*)(wr + FOUT);
        float4 w2 = *(const float4*)(wr + 2 * FOUT);
        float4 w3 = *(const float4*)(wr + 3 * FOUT);
        a0 = fmaf(xv.x, w0.x, a0); a1 = fmaf(xv.x, w0.y, a1);
        a2 = fmaf(xv.x, w0.z, a2); a3 = fmaf(xv.x, w0.w, a3);
        a0 = fmaf(xv.y, w1.x, a0); a1 = fmaf(xv.y, w1.y, a1);
        a2 = fmaf(xv.y, w1.z, a2); a3 = fmaf(xv.y, w1.w, a3);
        a0 = fmaf(xv.z, w2.x, a0); a1 = fmaf(xv.z, w2.y, a1);
        a2 = fmaf(xv.z, w2.z, a2); a3 = fmaf(xv.z, w2.w, a3);
        a0 = fmaf(xv.w, w3.x, a0); a1 = fmaf(xv.w, w3.y, a1);
        a2 = fmaf(xv.w, w3.z, a2); a3 = fmaf(xv.w, w3.w, a3);
    }
    unsigned short b0 = f2bf(a0), b1 = f2bf(a1), b2 = f2bf(a2), b3 = f2bf(a3);
    *(ushort4*)(h + (long)n * FOUT + fb) = make_ushort4(b0, b1, b2, b3);
    float q0 = bflo((unsigned)b0), q1 = bflo((unsigned)b1);
    float q2 = bflo((unsigned)b2), q3 = bflo((unsigned)b3);
    float vs = q0 * a_src[fb] + q1 * a_src[fb + 1] + q2 * a_src[fb + 2] + q3 * a_src[fb + 3];
    float vd = q0 * a_dst[fb] + q1 * a_dst[fb + 1] + q2 * a_dst[fb + 2] + q3 * a_dst[fb + 3];
#pragma unroll
    for (int o = 1; o < TPH; o <<= 1) {
        vs += __shfl_xor(vs, o);
        vd += __shfl_xor(vd, o);
    }
    if ((f4 % TPH) == 0) {
        int hh = f4 / TPH;
        esrc[n * HH + hh] = vs;
        edst[n * HH + hh] = vd;
    }
}

// plain GEMM with output row stride SO (shorts); layer 3: 40 feats at 80B rows
template <int FIN, int FOUT, int SO>
__global__ __launch_bounds__(256) void gemm_kernel(const float* __restrict__ x,
                                                   const float* __restrict__ W,
                                                   unsigned short* __restrict__ h, int N) {
    constexpr int F4 = FOUT / 4;
    __shared__ __align__(16) float Ws[FIN * FOUT];
    for (int i = threadIdx.x; i < FIN * FOUT; i += blockDim.x) Ws[i] = W[i];
    __syncthreads();
    int idx = blockIdx.x * blockDim.x + threadIdx.x;
    if (idx >= N * F4) return;
    int n = idx / F4, f4 = idx - n * F4;
    int fb = 4 * f4;
    const float4* xr = (const float4*)(x + (long)n * FIN);
    float a0 = 0.f, a1 = 0.f, a2 = 0.f, a3 = 0.f;
#pragma unroll
    for (int k4 = 0; k4 < FIN / 4; ++k4) {
        float4 xv = xr[k4];
        const float* wr = &Ws[(4 * k4) * FOUT + fb];
        float4 w0 = *(const float4*)(wr);
        float4 w1 = *(const float4*)(wr + FOUT);
        float4 w2 = *(const float4*)(wr + 2 * FOUT);
        float4 w3 = *(const float4*)(wr + 3 * FOUT);
        a0 = fmaf(xv.x, w0.x, a0); a1 = fmaf(xv.x, w0.y, a1);
        a2 = fmaf(xv.x, w0.z, a2); a3 = fmaf(xv.x, w0.w, a3);
        a0 = fmaf(xv.y, w1.x, a0); a1 = fmaf(xv.y, w1.y, a1);
        a2 = fmaf(xv.y, w1.z, a2); a3 = fmaf(xv.y, w1.w, a3);
        a0 = fmaf(xv.z, w2.x, a0); a1 = fmaf(xv.z, w2.y, a1);
        a2 = fmaf(xv.z, w2.z, a2); a3 = fmaf(xv.z, w2.w, a3);
        a0 = fmaf(xv.w, w3.x, a0); a1 = fmaf(xv.w, w3.y, a1);
        a2 = fmaf(xv.w, w3.z, a2); a3 = fmaf(xv.w, w3.w, a3);
    }
    *(ushort4*)(h + (long)n * SO + fb) = make_ushort4(f2bf(a0), f2bf(a1), f2bf(a2), f2bf(a3));
}

// attention logits for layer 3 (H=1), input row stride SO shorts, uint4 row read
template <int C, int SO>
__global__ void attn_kernel(const unsigned short* __restrict__ h,
                            const float* __restrict__ a_src,
                            const float* __restrict__ a_dst, float* __restrict__ esrc,
                            float* __restrict__ edst, int N) {
    int idx = blockIdx.x * blockDim.x + threadIdx.x;
    if (idx >= N) return;
    const uint4* hp = (const uint4*)(h + (long)idx * SO);
    float s = 0.f, d = 0.f;
#pragma unroll
    for (int c8 = 0; c8 < C / 8; ++c8) {
        uint4 v = hp[c8];
        int c = 8 * c8;
        s += bflo(v.x) * a_src[c] + bfhi(v.x) * a_src[c + 1];
        d += bflo(v.x) * a_dst[c] + bfhi(v.x) * a_dst[c + 1];
        s += bflo(v.y) * a_src[c + 2] + bfhi(v.y) * a_src[c + 3];
        d += bflo(v.y) * a_dst[c + 2] + bfhi(v.y) * a_dst[c + 3];
        s += bflo(v.z) * a_src[c + 4] + bfhi(v.z) * a_src[c + 5];
        d += bflo(v.z) * a_dst[c + 4] + bfhi(v.z) * a_dst[c + 5];
        s += bflo(v.w) * a_src[c + 6] + bfhi(v.w) * a_src[c + 7];
        d += bflo(v.w) * a_dst[c + 6] + bfhi(v.w) * a_dst[c + 7];
    }
    esrc[idx] = s;
    edst[idx] = d;
}

// ---------------- CSR gather aggregation ----------------
// Pipelined U-batches (issue all hv/es gathers + next ssrc before compute,
// pinned by sched_barrier). Tail folded via clamped indices + predicated ex.
template <int H, int C, int L, int G, int NPW, int FPL, int RSL, int U, bool ELU>
__global__ __launch_bounds__(256) void agg_kernel(
    const int* __restrict__ rowptr, const int* __restrict__ ssrc,
    const float* __restrict__ esrc, const float* __restrict__ edst,
    const unsigned short* __restrict__ hbuf, const float* __restrict__ b,
    float* __restrict__ out, int N) {
    constexpr int F = H * C;
    constexpr int AQ = (F + FPL - 1) / FPL;
    constexpr int S = L * G;
    static_assert(S * NPW == 64, "wave layout");
    static_assert(AQ <= L, "lanes cover features");
    int lane = threadIdx.x & 63;
    int wave = threadIdx.x >> 6;
    int sub = lane / S;
    int ls = lane - sub * S;
    int g = ls / L, q = ls - g * L;
    int n = (blockIdx.x * 4 + wave) * NPW + sub;
    if (n >= N) return;
    const bool act = (q < AQ);
    int h = act ? (FPL * q) / C : 0;
    int qa = act ? q : 0;
    float edn = edst[n * H + h];
    int beg = rowptr[n], end = rowptr[n + 1];
    int kend = end - 1;                   // deg >= 1 (self loop) -> always valid
    float sum = 0.f;
    float acc[FPL];
#pragma unroll
    for (int i = 0; i < FPL; ++i) acc[i] = 0.f;

    int k = beg + g;
    int ss[U];
#pragma unroll
    for (int u = 0; u < U; ++u) {
        int kk = k + u * G;
        ss[u] = ssrc[kk < kend ? kk : kend];
    }
    while (k < end) {
        uint4 hv4[U];
        uint2 hv2[U];
        float es[U];
#pragma unroll
        for (int u = 0; u < U; ++u) {
            if constexpr (FPL == 8) hv4[u] = ((const uint4*)hbuf)[ss[u] * RSL + qa];
            else hv2[u] = ((const uint2*)hbuf)[ss[u] * RSL + qa];
            es[u] = esrc[ss[u] * H + h];
        }
        int kn = k + U * G;
        int sn[U];
#pragma unroll
        for (int u = 0; u < U; ++u) {
            int kk = kn + u * G;
            sn[u] = ssrc[kk < kend ? kk : kend];
        }
        __builtin_amdgcn_sched_barrier(0);  // loads above must all issue first
#pragma unroll
        for (int u = 0; u < U; ++u) {
            float ex = (act && (k + u * G < end)) ? __expf(lrelu(es[u] + edn)) : 0.f;
            if constexpr (FPL == 8) {
                uint4 v = hv4[u];
                acc[0] = fmaf(ex, bflo(v.x), acc[0]); acc[1] = fmaf(ex, bfhi(v.x), acc[1]);
                acc[2] = fmaf(ex, bflo(v.y), acc[2]); acc[3] = fmaf(ex, bfhi(v.y), acc[3]);
                acc[4] = fmaf(ex, bflo(v.z), acc[4]); acc[5] = fmaf(ex, bfhi(v.z), acc[5]);
                acc[6] = fmaf(ex, bflo(v.w), acc[6]); acc[7] = fmaf(ex, bfhi(v.w), acc[7]);
            } else {
                uint2 v = hv2[u];
                acc[0] = fmaf(ex, bflo(v.x), acc[0]); acc[1] = fmaf(ex, bfhi(v.x), acc[1]);
                acc[2] = fmaf(ex, bflo(v.y), acc[2]); acc[3] = fmaf(ex, bfhi(v.y), acc[3]);
            }
            sum += ex;
        }
#pragma unroll
        for (int u = 0; u < U; ++u) ss[u] = sn[u];
        k = kn;
    }
#pragma unroll
    for (int step = L; step < S; step <<= 1) {
        sum += __shfl_xor(sum, step);
#pragma unroll
        for (int i = 0; i < FPL; ++i) acc[i] += __shfl_xor(acc[i], step);
    }
    if (g == 0 && act) {
        float inv = 1.f / (sum + 1e-16f);
        float v[FPL];
#pragma unroll
        for (int i = 0; i < FPL; ++i) {
            v[i] = acc[i] * inv + b[FPL * q + i];
            if (ELU) v[i] = v[i] > 0.f ? v[i] : __expf(v[i]) - 1.f;
        }
        float* op = out + n * F + FPL * q;
#pragma unroll
        for (int i = 0; i < FPL; i += 4)
            *(float4*)(op + i) = make_float4(v[i], v[i + 1], v[i + 2], v[i + 3]);
    }
}

static inline int cdiv(long a, int b) { return (int)((a + b - 1) / b); }

extern "C" void kernel_launch(void* const* d_in, const int* in_sizes, int n_in,
                              void* d_out, int out_size, void* d_ws, size_t ws_size,
                              hipStream_t stream) {
    const float* x1 = (const float*)d_in[0];
    const int* ei = (const int*)d_in[1];
    const int* src = ei;
    const int* dst = ei + NE;
    const float* W1 = (const float*)d_in[2];
    const float* as1 = (const float*)d_in[3];
    const float* ad1 = (const float*)d_in[4];
    const float* b1 = (const float*)d_in[5];
    const float* W2 = (const float*)d_in[6];
    const float* as2 = (const float*)d_in[7];
    const float* ad2 = (const float*)d_in[8];
    const float* b2 = (const float*)d_in[9];
    const float* W3 = (const float*)d_in[10];
    const float* as3 = (const float*)d_in[11];
    const float* ad3 = (const float*)d_in[12];
    const float* b3 = (const float*)d_in[13];
    float* out = (float*)d_out;

    // workspace carve (~60 MB)
    char* wsb = (char*)d_ws;
    unsigned short* hbuf = (unsigned short*)wsb;  wsb += (long)NN * 64 * 2;
    float* x2 = (float*)wsb;         wsb += (long)NN * 16 * 4;
    float* x3 = (float*)wsb;         wsb += (long)NN * 64 * 4;
    float* esrc = (float*)wsb;       wsb += (long)NN * 8 * 4;
    float* edst = (float*)wsb;       wsb += (long)NN * 8 * 4;
    int* ssrc = (int*)wsb;           wsb += (long)ET * 4;
    int* rowptr = (int*)wsb;         wsb += (long)(NN + 1) * 4;
    int* deg = (int*)wsb;            wsb += (long)NN * 4;
    int* cur = (int*)wsb;            wsb += (long)NN * 4;
    int* tot = (int*)wsb;            wsb += (long)128 * 4;

    const int B = 256;
    const int NSB = cdiv(NN, 1024);      // 98 scan blocks

    // ---- CSR build: deg -> scan -> fill (once, reused by all 3 layers) ----
    initdeg_kernel<<<cdiv(NN, B), B, 0, stream>>>(deg);
    deg_kernel<<<2048, B, 0, stream>>>(dst, deg);
    scan1_kernel<<<NSB, 1024, 0, stream>>>(deg, rowptr, tot);
    scan2_kernel<<<1, 128, 0, stream>>>(tot, NSB);
    scan3_kernel<<<NSB, 1024, 0, stream>>>(rowptr, tot, cur, ssrc);
    fill_kernel<<<2048, B, 0, stream>>>(src, dst, cur, ssrc);

    // ---- Layer 1: 128 -> H=4, C=4 (concat 16), ELU;  FPL=4, RSL=4, G=8, NPW=2, U=5 ----
    gemm_attn_kernel<128, 16, 4><<<cdiv((long)NN * 4, B), B, 0, stream>>>(
        x1, W1, as1, ad1, hbuf, esrc, edst, NN);
    agg_kernel<4, 4, 4, 8, 2, 4, 4, 5, true><<<cdiv(NN, 8), B, 0, stream>>>(
        rowptr, ssrc, esrc, edst, hbuf, b1, x2, NN);

    // ---- Layer 2: 16 -> H=8, C=8 (concat 64), ELU;  FPL=8, RSL=8, G=8, U=5 ----
    gemm_attn_kernel<16, 64, 8><<<cdiv((long)NN * 16, B), B, 0, stream>>>(
        x2, W2, as2, ad2, hbuf, esrc, edst, NN);
    agg_kernel<8, 8, 8, 8, 1, 8, 8, 5, true><<<cdiv(NN, 4), B, 0, stream>>>(
        rowptr, ssrc, esrc, edst, hbuf, b2, x3, NN);

    // ---- Layer 3: 64 -> H=1, C=40, no concat, no ELU; rows packed at 80B (RSL=5) ----
    gemm_kernel<64, 40, 40><<<cdiv((long)NN * 10, B), B, 0, stream>>>(x3, W3, hbuf, NN);
    attn_kernel<40, 40><<<cdiv(NN, B), B, 0, stream>>>(hbuf, as3, ad3, esrc, edst, NN);
    agg_kernel<1, 40, 8, 8, 1, 8, 5, 5, false><<<cdiv(NN, 4), B, 0, stream>>>(
        rowptr, ssrc, esrc, edst, hbuf, b3, out, NN);
}

// Round 7
// 424.861 us; speedup vs baseline: 1.8342x; 1.8342x over previous
//
#include <hip/hip_runtime.h>

#define NN 100000
#define NE 3200000
#define ET (NE + NN)
#define NEG_SLOPE 0.2f
#define BSH 7
#define WIN (1 << BSH)                     // 128 nodes per bucket
#define NBUC ((NN + WIN - 1) >> BSH)       // 782 buckets
#define NBLK 256                           // scatter blocks (one per CU)
#define EPB ((ET + NBLK - 1) / NBLK)       // edges per scatter block

// XCD-swizzled region column: blocks b and b+8 (same XCD under round-robin
// dispatch) get adjacent columns, so a 128B line of cnt/tmpp is filled by one
// XCD only -> no cross-XCD partial-line ping-pong (round-5/6 counters showed
// 6.4x / 15x write amplification from exactly that).
__device__ __host__ __forceinline__ int swz(int b) {
    return (b & 7) * (NBLK / 8) + (b >> 3);
}

__device__ __forceinline__ float lrelu(float v) { return v > 0.f ? v : NEG_SLOPE * v; }

// bf16 <-> f32
__device__ __forceinline__ unsigned short f2bf(float x) {
    unsigned u = __float_as_uint(x);
    return (unsigned short)((u + 0x7fffu + ((u >> 16) & 1u)) >> 16);
}
__device__ __forceinline__ float bflo(unsigned u) { return __uint_as_float(u << 16); }
__device__ __forceinline__ float bfhi(unsigned u) { return __uint_as_float(u & 0xffff0000u); }

// ---------------- binned CSR build (all write regions block-private) ----------------

__global__ __launch_bounds__(1024) void cnt_kernel(const int* __restrict__ dst,
                                                   int* __restrict__ cnt) {
    __shared__ int h[NBUC];
    for (int i = threadIdx.x; i < NBUC; i += 1024) h[i] = 0;
    __syncthreads();
    int lo = blockIdx.x * EPB;
    int hi = lo + EPB; if (hi > ET) hi = ET;
    for (int k = lo + threadIdx.x; k < hi; k += 1024) {
        int d = (k < NE) ? dst[k] : k - NE;   // self loops appended
        atomicAdd(&h[d >> BSH], 1);
    }
    __syncthreads();
    int col = swz(blockIdx.x);
    for (int i = threadIdx.x; i < NBUC; i += 1024)
        cnt[i * NBLK + col] = h[i];
}

__global__ __launch_bounds__(256) void rowsum_kernel(const int* __restrict__ cnt,
                                                     int* __restrict__ tot) {
    int wave = threadIdx.x >> 6, lane = threadIdx.x & 63;
    int b = blockIdx.x * 4 + wave;
    if (b >= NBUC) return;
    int4 v = ((const int4*)(cnt + b * NBLK))[lane];
    int s = v.x + v.y + v.z + v.w;
#pragma unroll
    for (int off = 32; off; off >>= 1) s += __shfl_xor(s, off);
    if (lane == 0) tot[b] = s;
}

__global__ __launch_bounds__(1024) void scan_kernel(const int* __restrict__ tot,
                                                    int* __restrict__ bstart) {
    __shared__ int t[1024];
    int b = threadIdx.x;
    int s = (b < NBUC) ? tot[b] : 0;
    t[b] = s;
    __syncthreads();
    for (int off = 1; off < 1024; off <<= 1) {
        int v = (b >= off) ? t[b - off] : 0;
        __syncthreads();
        t[b] += v;
        __syncthreads();
    }
    if (b < NBUC) bstart[b] = t[b] - s;
    if (b == 0) bstart[NBUC] = ET;
}

__global__ __launch_bounds__(256) void base_kernel(int* __restrict__ cnt,
                                                   const int* __restrict__ bstart) {
    int wave = threadIdx.x >> 6, lane = threadIdx.x & 63;
    int b = blockIdx.x * 4 + wave;
    if (b >= NBUC) return;
    int run = bstart[b];
    for (int c0 = 0; c0 < NBLK; c0 += 64) {
        int v = cnt[b * NBLK + c0 + lane];
        int x = v;
#pragma unroll
        for (int off = 1; off < 64; off <<= 1) {
            int y = __shfl_up(x, off);
            if (lane >= off) x += y;
        }
        cnt[b * NBLK + c0 + lane] = run + x - v;
        run += __shfl(x, 63);
    }
}

__global__ __launch_bounds__(1024) void scatter_kernel(const int* __restrict__ src,
                                                       const int* __restrict__ dst,
                                                       const int* __restrict__ base,
                                                       unsigned* __restrict__ tmpp) {
    __shared__ int loff[NBUC];
    int col = swz(blockIdx.x);
    for (int i = threadIdx.x; i < NBUC; i += 1024) loff[i] = base[i * NBLK + col];
    __syncthreads();
    int lo = blockIdx.x * EPB;
    int hi = lo + EPB; if (hi > ET) hi = ET;
    for (int k = lo + threadIdx.x; k < hi; k += 1024) {
        int s, d;
        if (k < NE) { s = src[k]; d = dst[k]; }
        else { s = d = k - NE; }
        int p = atomicAdd(&loff[d >> BSH], 1);
        tmpp[p] = (unsigned)s | ((unsigned)(d & (WIN - 1)) << 17);
    }
}

__global__ __launch_bounds__(512) void sort_kernel(const int* __restrict__ bstart,
                                                   const unsigned* __restrict__ tmpp,
                                                   int* __restrict__ rowptr,
                                                   int* __restrict__ ssrc) {
    __shared__ int hist[WIN];
    __shared__ int scan[WIN];
    __shared__ int cur[WIN];
    int buc = blockIdx.x;
    int nlo = buc << BSH;
    int nwin = NN - nlo; if (nwin > WIN) nwin = WIN;
    int lo = bstart[buc], hi = bstart[buc + 1];
    int tid = threadIdx.x;
    if (tid < WIN) hist[tid] = 0;
    __syncthreads();
    for (int k = lo + tid; k < hi; k += 512)
        atomicAdd(&hist[tmpp[k] >> 17], 1);
    __syncthreads();
    if (tid < WIN) scan[tid] = hist[tid];
    __syncthreads();
    for (int off = 1; off < WIN; off <<= 1) {
        int v = (tid >= off && tid < WIN) ? scan[tid - off] : 0;
        __syncthreads();
        if (tid < WIN) scan[tid] += v;
        __syncthreads();
    }
    if (tid < WIN) {
        int ex = scan[tid] - hist[tid];
        cur[tid] = ex;
        if (tid < nwin) rowptr[nlo + tid] = lo + ex;
    }
    if (buc == 0 && tid == 0) rowptr[NN] = ET;
    __syncthreads();
    for (int k = lo + tid; k < hi; k += 512) {
        unsigned e = tmpp[k];
        int p = atomicAdd(&cur[e >> 17], 1);
        ssrc[lo + p] = (int)(e & 0x1FFFFu);
    }
}

// ---------------- dense per-layer kernels ----------------

// fused GEMM + attention logits. Each thread computes 4 consecutive output
// features for one node: float4 x loads, float4 (b128) LDS W reads.
template <int FIN, int FOUT, int C>
__global__ __launch_bounds__(256) void gemm_attn_kernel(
    const float* __restrict__ x, const float* __restrict__ W,
    const float* __restrict__ a_src, const float* __restrict__ a_dst,
    unsigned short* __restrict__ h, float* __restrict__ esrc,
    float* __restrict__ edst, int N) {
    constexpr int HH = FOUT / C;
    constexpr int F4 = FOUT / 4;
    constexpr int TPH = C / 4;           // threads per head
    __shared__ __align__(16) float Ws[FIN * FOUT];
    for (int i = threadIdx.x; i < FIN * FOUT; i += blockDim.x) Ws[i] = W[i];
    __syncthreads();
    int idx = blockIdx.x * blockDim.x + threadIdx.x;
    if (idx >= N * F4) return;
    int n = idx / F4, f4 = idx - n * F4;
    int fb = 4 * f4;
    const float4* xr = (const float4*)(x + (long)n * FIN);
    float a0 = 0.f, a1 = 0.f, a2 = 0.f, a3 = 0.f;
#pragma unroll
    for (int k4 = 0; k4 < FIN / 4; ++k4) {
        float4 xv = xr[k4];
        const float* wr = &Ws[(4 * k4) * FOUT + fb];
        float4 w0 = *(const float4*)(wr);
        float4 w1 = *(const float4*)(wr + FOUT);
        float4 w2 = *(const float4*)(wr + 2 * FOUT);
        float4 w3 = *(const float4*)(wr + 3 * FOUT);
        a0 = fmaf(xv.x, w0.x, a0); a1 = fmaf(xv.x, w0.y, a1);
        a2 = fmaf(xv.x, w0.z, a2); a3 = fmaf(xv.x, w0.w, a3);
        a0 = fmaf(xv.y, w1.x, a0); a1 = fmaf(xv.y, w1.y, a1);
        a2 = fmaf(xv.y, w1.z, a2); a3 = fmaf(xv.y, w1.w, a3);
        a0 = fmaf(xv.z, w2.x, a0); a1 = fmaf(xv.z, w2.y, a1);
        a2 = fmaf(xv.z, w2.z, a2); a3 = fmaf(xv.z, w2.w, a3);
        a0 = fmaf(xv.w, w3.x, a0); a1 = fmaf(xv.w, w3.y, a1);
        a2 = fmaf(xv.w, w3.z, a2); a3 = fmaf(xv.w, w3.w, a3);
    }
    unsigned short b0 = f2bf(a0), b1 = f2bf(a1), b2 = f2bf(a2), b3 = f2bf(a3);
    *(ushort4*)(h + (long)n * FOUT + fb) = make_ushort4(b0, b1, b2, b3);
    float q0 = bflo((unsigned)b0), q1 = bflo((unsigned)b1);
    float q2 = bflo((unsigned)b2), q3 = bflo((unsigned)b3);
    float vs = q0 * a_src[fb] + q1 * a_src[fb + 1] + q2 * a_src[fb + 2] + q3 * a_src[fb + 3];
    float vd = q0 * a_dst[fb] + q1 * a_dst[fb + 1] + q2 * a_dst[fb + 2] + q3 * a_dst[fb + 3];
#pragma unroll
    for (int o = 1; o < TPH; o <<= 1) {
        vs += __shfl_xor(vs, o);
        vd += __shfl_xor(vd, o);
    }
    if ((f4 % TPH) == 0) {
        int hh = f4 / TPH;
        esrc[n * HH + hh] = vs;
        edst[n * HH + hh] = vd;
    }
}

// plain GEMM with output row stride SO (shorts); layer 3: 40 feats at 80B rows
template <int FIN, int FOUT, int SO>
__global__ __launch_bounds__(256) void gemm_kernel(const float* __restrict__ x,
                                                   const float* __restrict__ W,
                                                   unsigned short* __restrict__ h, int N) {
    constexpr int F4 = FOUT / 4;
    __shared__ __align__(16) float Ws[FIN * FOUT];
    for (int i = threadIdx.x; i < FIN * FOUT; i += blockDim.x) Ws[i] = W[i];
    __syncthreads();
    int idx = blockIdx.x * blockDim.x + threadIdx.x;
    if (idx >= N * F4) return;
    int n = idx / F4, f4 = idx - n * F4;
    int fb = 4 * f4;
    const float4* xr = (const float4*)(x + (long)n * FIN);
    float a0 = 0.f, a1 = 0.f, a2 = 0.f, a3 = 0.f;
#pragma unroll
    for (int k4 = 0; k4 < FIN / 4; ++k4) {
        float4 xv = xr[k4];
        const float* wr = &Ws[(4 * k4) * FOUT + fb];
        float4 w0 = *(const float4*)(wr);
        float4 w1 = *(const float4*)(wr + FOUT);
        float4 w2 = *(const float4*)(wr + 2 * FOUT);
        float4 w3 = *(const float4*)(wr + 3 * FOUT);
        a0 = fmaf(xv.x, w0.x, a0); a1 = fmaf(xv.x, w0.y, a1);
        a2 = fmaf(xv.x, w0.z, a2); a3 = fmaf(xv.x, w0.w, a3);
        a0 = fmaf(xv.y, w1.x, a0); a1 = fmaf(xv.y, w1.y, a1);
        a2 = fmaf(xv.y, w1.z, a2); a3 = fmaf(xv.y, w1.w, a3);
        a0 = fmaf(xv.z, w2.x, a0); a1 = fmaf(xv.z, w2.y, a1);
        a2 = fmaf(xv.z, w2.z, a2); a3 = fmaf(xv.z, w2.w, a3);
        a0 = fmaf(xv.w, w3.x, a0); a1 = fmaf(xv.w, w3.y, a1);
        a2 = fmaf(xv.w, w3.z, a2); a3 = fmaf(xv.w, w3.w, a3);
    }
    *(ushort4*)(h + (long)n * SO + fb) = make_ushort4(f2bf(a0), f2bf(a1), f2bf(a2), f2bf(a3));
}

// attention logits for layer 3 (H=1), input row stride SO shorts, uint4 row read
template <int C, int SO>
__global__ void attn_kernel(const unsigned short* __restrict__ h,
                            const float* __restrict__ a_src,
                            const float* __restrict__ a_dst, float* __restrict__ esrc,
                            float* __restrict__ edst, int N) {
    int idx = blockIdx.x * blockDim.x + threadIdx.x;
    if (idx >= N) return;
    const uint4* hp = (const uint4*)(h + (long)idx * SO);
    float s = 0.f, d = 0.f;
#pragma unroll
    for (int c8 = 0; c8 < C / 8; ++c8) {
        uint4 v = hp[c8];
        int c = 8 * c8;
        s += bflo(v.x) * a_src[c] + bfhi(v.x) * a_src[c + 1];
        d += bflo(v.x) * a_dst[c] + bfhi(v.x) * a_dst[c + 1];
        s += bflo(v.y) * a_src[c + 2] + bfhi(v.y) * a_src[c + 3];
        d += bflo(v.y) * a_dst[c + 2] + bfhi(v.y) * a_dst[c + 3];
        s += bflo(v.z) * a_src[c + 4] + bfhi(v.z) * a_src[c + 5];
        d += bflo(v.z) * a_dst[c + 4] + bfhi(v.z) * a_dst[c + 5];
        s += bflo(v.w) * a_src[c + 6] + bfhi(v.w) * a_src[c + 7];
        d += bflo(v.w) * a_dst[c + 6] + bfhi(v.w) * a_dst[c + 7];
    }
    esrc[idx] = s;
    edst[idx] = d;
}

// ---------------- CSR gather aggregation ----------------
// Pipelined U-batches (issue all hv/es gathers + next ssrc before compute,
// pinned by sched_barrier). Tail folded via clamped indices + predicated ex.
template <int H, int C, int L, int G, int NPW, int FPL, int RSL, int U, bool ELU>
__global__ __launch_bounds__(256) void agg_kernel(
    const int* __restrict__ rowptr, const int* __restrict__ ssrc,
    const float* __restrict__ esrc, const float* __restrict__ edst,
    const unsigned short* __restrict__ hbuf, const float* __restrict__ b,
    float* __restrict__ out, int N) {
    constexpr int F = H * C;
    constexpr int AQ = (F + FPL - 1) / FPL;
    constexpr int S = L * G;
    static_assert(S * NPW == 64, "wave layout");
    static_assert(AQ <= L, "lanes cover features");
    int lane = threadIdx.x & 63;
    int wave = threadIdx.x >> 6;
    int sub = lane / S;
    int ls = lane - sub * S;
    int g = ls / L, q = ls - g * L;
    int n = (blockIdx.x * 4 + wave) * NPW + sub;
    if (n >= N) return;
    const bool act = (q < AQ);
    int h = act ? (FPL * q) / C : 0;
    int qa = act ? q : 0;
    float edn = edst[n * H + h];
    int beg = rowptr[n], end = rowptr[n + 1];
    int kend = end - 1;                   // deg >= 1 (self loop) -> always valid
    float sum = 0.f;
    float acc[FPL];
#pragma unroll
    for (int i = 0; i < FPL; ++i) acc[i] = 0.f;

    int k = beg + g;
    int ss[U];
#pragma unroll
    for (int u = 0; u < U; ++u) {
        int kk = k + u * G;
        ss[u] = ssrc[kk < kend ? kk : kend];
    }
    while (k < end) {
        uint4 hv4[U];
        uint2 hv2[U];
        float es[U];
#pragma unroll
        for (int u = 0; u < U; ++u) {
            if constexpr (FPL == 8) hv4[u] = ((const uint4*)hbuf)[ss[u] * RSL + qa];
            else hv2[u] = ((const uint2*)hbuf)[ss[u] * RSL + qa];
            es[u] = esrc[ss[u] * H + h];
        }
        int kn = k + U * G;
        int sn[U];
#pragma unroll
        for (int u = 0; u < U; ++u) {
            int kk = kn + u * G;
            sn[u] = ssrc[kk < kend ? kk : kend];
        }
        __builtin_amdgcn_sched_barrier(0);  // loads above must all issue first
#pragma unroll
        for (int u = 0; u < U; ++u) {
            float ex = (act && (k + u * G < end)) ? __expf(lrelu(es[u] + edn)) : 0.f;
            if constexpr (FPL == 8) {
                uint4 v = hv4[u];
                acc[0] = fmaf(ex, bflo(v.x), acc[0]); acc[1] = fmaf(ex, bfhi(v.x), acc[1]);
                acc[2] = fmaf(ex, bflo(v.y), acc[2]); acc[3] = fmaf(ex, bfhi(v.y), acc[3]);
                acc[4] = fmaf(ex, bflo(v.z), acc[4]); acc[5] = fmaf(ex, bfhi(v.z), acc[5]);
                acc[6] = fmaf(ex, bflo(v.w), acc[6]); acc[7] = fmaf(ex, bfhi(v.w), acc[7]);
            } else {
                uint2 v = hv2[u];
                acc[0] = fmaf(ex, bflo(v.x), acc[0]); acc[1] = fmaf(ex, bfhi(v.x), acc[1]);
                acc[2] = fmaf(ex, bflo(v.y), acc[2]); acc[3] = fmaf(ex, bfhi(v.y), acc[3]);
            }
            sum += ex;
        }
#pragma unroll
        for (int u = 0; u < U; ++u) ss[u] = sn[u];
        k = kn;
    }
#pragma unroll
    for (int step = L; step < S; step <<= 1) {
        sum += __shfl_xor(sum, step);
#pragma unroll
        for (int i = 0; i < FPL; ++i) acc[i] += __shfl_xor(acc[i], step);
    }
    if (g == 0 && act) {
        float inv = 1.f / (sum + 1e-16f);
        float v[FPL];
#pragma unroll
        for (int i = 0; i < FPL; ++i) {
            v[i] = acc[i] * inv + b[FPL * q + i];
            if (ELU) v[i] = v[i] > 0.f ? v[i] : __expf(v[i]) - 1.f;
        }
        float* op = out + n * F + FPL * q;
#pragma unroll
        for (int i = 0; i < FPL; i += 4)
            *(float4*)(op + i) = make_float4(v[i], v[i + 1], v[i + 2], v[i + 3]);
    }
}

static inline int cdiv(long a, int b) { return (int)((a + b - 1) / b); }

extern "C" void kernel_launch(void* const* d_in, const int* in_sizes, int n_in,
                              void* d_out, int out_size, void* d_ws, size_t ws_size,
                              hipStream_t stream) {
    const float* x1 = (const float*)d_in[0];
    const int* ei = (const int*)d_in[1];
    const int* src = ei;
    const int* dst = ei + NE;
    const float* W1 = (const float*)d_in[2];
    const float* as1 = (const float*)d_in[3];
    const float* ad1 = (const float*)d_in[4];
    const float* b1 = (const float*)d_in[5];
    const float* W2 = (const float*)d_in[6];
    const float* as2 = (const float*)d_in[7];
    const float* ad2 = (const float*)d_in[8];
    const float* b2 = (const float*)d_in[9];
    const float* W3 = (const float*)d_in[10];
    const float* as3 = (const float*)d_in[11];
    const float* ad3 = (const float*)d_in[12];
    const float* b3 = (const float*)d_in[13];
    float* out = (float*)d_out;

    // workspace carve (~80 MB)
    char* wsb = (char*)d_ws;
    unsigned short* hbuf = (unsigned short*)wsb;  wsb += (long)NN * 64 * 2;
    float* x2 = (float*)wsb;         wsb += (long)NN * 16 * 4;
    float* x3 = (float*)wsb;         wsb += (long)NN * 64 * 4;
    float* esrc = (float*)wsb;       wsb += (long)NN * 8 * 4;
    float* edst = (float*)wsb;       wsb += (long)NN * 8 * 4;
    unsigned* tmpp = (unsigned*)wsb; wsb += (long)ET * 4;
    int* ssrc = (int*)wsb;           wsb += (long)ET * 4;
    int* rowptr = (int*)wsb;         wsb += (long)(NN + 1) * 4;
    int* cnt = (int*)wsb;            wsb += (long)NBUC * NBLK * 4;
    int* bstart = (int*)wsb;         wsb += (long)(NBUC + 1) * 4;
    int* tot = (int*)wsb;            wsb += (long)NBUC * 4;

    const int B = 256;

    // ---- CSR build (once, reused by all 3 layers) ----
    cnt_kernel<<<NBLK, 1024, 0, stream>>>(dst, cnt);
    rowsum_kernel<<<cdiv(NBUC, 4), B, 0, stream>>>(cnt, tot);
    scan_kernel<<<1, 1024, 0, stream>>>(tot, bstart);
    base_kernel<<<cdiv(NBUC, 4), B, 0, stream>>>(cnt, bstart);
    scatter_kernel<<<NBLK, 1024, 0, stream>>>(src, dst, cnt, tmpp);
    sort_kernel<<<NBUC, 512, 0, stream>>>(bstart, tmpp, rowptr, ssrc);

    // ---- Layer 1: 128 -> H=4, C=4 (concat 16), ELU;  FPL=4, RSL=4, G=8, NPW=2, U=5 ----
    gemm_attn_kernel<128, 16, 4><<<cdiv((long)NN * 4, B), B, 0, stream>>>(
        x1, W1, as1, ad1, hbuf, esrc, edst, NN);
    agg_kernel<4, 4, 4, 8, 2, 4, 4, 5, true><<<cdiv(NN, 8), B, 0, stream>>>(
        rowptr, ssrc, esrc, edst, hbuf, b1, x2, NN);

    // ---- Layer 2: 16 -> H=8, C=8 (concat 64), ELU;  FPL=8, RSL=8, G=8, U=5 ----
    gemm_attn_kernel<16, 64, 8><<<cdiv((long)NN * 16, B), B, 0, stream>>>(
        x2, W2, as2, ad2, hbuf, esrc, edst, NN);
    agg_kernel<8, 8, 8, 8, 1, 8, 8, 5, true><<<cdiv(NN, 4), B, 0, stream>>>(
        rowptr, ssrc, esrc, edst, hbuf, b2, x3, NN);

    // ---- Layer 3: 64 -> H=1, C=40, no concat, no ELU; rows packed at 80B (RSL=5) ----
    gemm_kernel<64, 40, 40><<<cdiv((long)NN * 10, B), B, 0, stream>>>(x3, W3, hbuf, NN);
    attn_kernel<40, 40><<<cdiv(NN, B), B, 0, stream>>>(hbuf, as3, ad3, esrc, edst, NN);
    agg_kernel<1, 40, 8, 8, 1, 8, 5, 5, false><<<cdiv(NN, 4), B, 0, stream>>>(
        rowptr, ssrc, esrc, edst, hbuf, b3, out, NN);
}